// Round 7
// baseline (673.853 us; speedup 1.0000x reference)
//
#include <hip/hip_runtime.h>
#include <hip/hip_bf16.h>
#include <stdint.h>

// y = sum_{k=0}^{3} h_k * S^k X,  X [8192,128] f32, S [8192,8192] f32.
// Persistent mega-kernel (512 blocks x 512 thr, all co-resident by construction:
// 48KB LDS -> 3 blk/CU by LDS, VGPR<=128 -> >=2 blk/CU, grid 512 = 2x256 CUs).
// Manual grid barrier: agent-scope atomic counters in ws, zeroed via
// hipMemsetAsync each launch. Phases:
//   A: convert own 64x2048 A-slice f32->bf16 (linear, read S exactly once)
//      + prep (y=h0*X, ZT0=X^T bf16)
//   3x: gemm (BM=64,BN=128,BK=64, KS=4 k-split, global_load_lds 16B,
//       XOR-swizzled LDS, 2-buffer counted-vmcnt) -> P ; bar ; combine ; bar

typedef __attribute__((ext_vector_type(8))) short     bf16x8;
typedef __attribute__((ext_vector_type(8))) uint16_t  u16x8;
typedef __attribute__((ext_vector_type(4))) float     f32x4;

#define NN 8192
#define NF 128
#define ZSTRIDE (8192 + 64)
#define GRID 512

#define WAITV(n) asm volatile("s_waitcnt vmcnt(" #n ")" ::: "memory")
#define WAITL0   asm volatile("s_waitcnt lgkmcnt(0)" ::: "memory")

__device__ inline uint16_t f2bf(float f) {
    uint32_t u = __builtin_bit_cast(uint32_t, f);
    u += 0x7fffu + ((u >> 16) & 1u);     // round-to-nearest-even
    return (uint16_t)(u >> 16);
}

__device__ inline void gl2lds16(const void* g, uint8_t* l) {
    __builtin_amdgcn_global_load_lds(
        (const __attribute__((address_space(1))) uint32_t*)g,
        (__attribute__((address_space(3))) uint32_t*)l,
        16, 0, 0);
}

__device__ inline bf16x8 ld16(const uint8_t* p) {
    return __builtin_bit_cast(bf16x8, *(const u16x8*)p);
}

// device-scope grid barrier; ctr[idx] zeroed by host-side memset each launch
__device__ inline void gridbar(uint32_t* ctr, int idx) {
    __syncthreads();                      // drains vmcnt/lgkmcnt, block-local
    if (threadIdx.x == 0) {
        __threadfence();                  // make my writes agent-visible
        __hip_atomic_fetch_add(ctr + idx, 1u, __ATOMIC_ACQ_REL,
                               __HIP_MEMORY_SCOPE_AGENT);
        uint32_t v;
        do {
            __builtin_amdgcn_s_sleep(2);
            v = __hip_atomic_load(ctr + idx, __ATOMIC_ACQUIRE,
                                  __HIP_MEMORY_SCOPE_AGENT);
        } while (v < GRID);
    }
    __syncthreads();
}

// ---- shared GEMM core: 2-buffer counted-vmcnt K-loop (measured ~23us r3) ---
template<int NT>
__device__ inline void gemm_core(const uint16_t* asrc, const uint16_t* bsrc,
                                 uint8_t* smem, int t, f32x4 (&acc)[4],
                                 int aoff, int bof) {
    auto stage = [&](int buf, int kt) {
        const int ko = kt * 64;
        uint8_t* b = smem + buf * 24576;
        gl2lds16(asrc + ko, b + t * 16);
        gl2lds16(bsrc + ko, b + 8192 + t * 16);
        gl2lds16(bsrc + (size_t)64 * ZSTRIDE + ko, b + 16384 + t * 16);
    };
    stage(0, 0);
    int cur = 0;
#pragma unroll 1
    for (int kt = 0; kt < NT; ++kt) {
        if (kt + 1 < NT) {
            stage(cur ^ 1, kt + 1);
            WAITV(3);                 // stage(kt) done; stage(kt+1) in flight
        } else {
            WAITV(0);
        }
        __builtin_amdgcn_s_barrier();
        __builtin_amdgcn_sched_barrier(0);
        const uint8_t* bb = smem + cur * 24576;
        bf16x8 a0 = ld16(bb + aoff);
        bf16x8 a1 = ld16(bb + (aoff ^ 64));
#pragma unroll
        for (int ct = 0; ct < 4; ++ct) {
            acc[ct] = __builtin_amdgcn_mfma_f32_16x16x32_bf16(
                a0, ld16(bb + bof + ct * 16 * 128), acc[ct], 0, 0, 0);
            acc[ct] = __builtin_amdgcn_mfma_f32_16x16x32_bf16(
                a1, ld16(bb + ((bof + ct * 16 * 128) ^ 64)), acc[ct], 0, 0, 0);
        }
        WAITL0;
        __builtin_amdgcn_sched_barrier(0);
        __builtin_amdgcn_s_barrier();
        cur ^= 1;
    }
}

// ---------------- mega-kernel phase helpers ---------------------------------

__device__ void mega_gemm(const uint16_t* S16, const uint16_t* ZTin,
                          float* P, uint8_t* smem, int mt, int ks, int t) {
    const int lane = t & 63, w = t >> 6, m = lane & 15, g = lane >> 4;
    const int rt = w & 3, ch = w >> 2;
    const int r0 = mt * 64, kb = ks * 2048;
    const int srow = t >> 3, sc = t & 7;
    const int scs  = (sc ^ (srow & 7)) << 3;
    const uint16_t* asrc = S16  + (size_t)(r0 + srow) * NN + kb + scs;
    const uint16_t* bsrc = ZTin + (size_t)srow * ZSTRIDE   + kb + scs;
    const int sw   = m & 7;
    const int aoff = (rt * 16 + m) * 128 + ((g ^ sw) << 4);
    const int bof  = 8192 + (ch * 64 + m) * 128 + ((g ^ sw) << 4);
    f32x4 acc[4] = {};
    gemm_core<32>(asrc, bsrc, smem, t, acc, aoff, bof);
    float* pb = P + ((size_t)ks * NN + r0 + rt * 16 + 4 * g) * NF + ch * 64 + m;
#pragma unroll
    for (int ct = 0; ct < 4; ++ct)
#pragma unroll
        for (int i = 0; i < 4; ++i)
            pb[(size_t)i * NF + ct * 16] = acc[ct][i];
}

__device__ void mega_combine(const float* P, float* y, uint16_t* ZTout,
                             float hk, uint8_t* smem, int bx, int t) {
    float* tile = (float*)smem;           // [16][132]
    const int r0 = bx * 16;
    const int row = t >> 5, colc = t & 31;
    const size_t off = (size_t)(r0 + row) * NF + colc * 4;
    f32x4 s = *(const f32x4*)(P + off);
#pragma unroll
    for (int k = 1; k < 4; ++k)
        s += *(const f32x4*)(P + (size_t)k * NN * NF + off);
    f32x4 yv = *(const f32x4*)(y + off);
    *(f32x4*)(y + off) = yv + hk * s;
    if (ZTout) {
        *(f32x4*)&tile[row * 132 + colc * 4] = s;
        __syncthreads();
        if (t < 256) {
            const int c = t >> 1, rh = t & 1;
            u16x8 pk;
#pragma unroll
            for (int e = 0; e < 8; ++e) pk[e] = f2bf(tile[(rh * 8 + e) * 132 + c]);
            *(u16x8*)(ZTout + (size_t)c * ZSTRIDE + r0 + rh * 8) = pk;
        }
    }
}

__global__ __launch_bounds__(512, 4) void k_mega(
    const float* __restrict__ S, const float* __restrict__ X,
    const float* __restrict__ coeff, float* __restrict__ y,
    uint16_t* ZT0, uint16_t* ZT1, uint16_t* S16, float* P, uint32_t* bar)
{
    __shared__ __align__(16) uint8_t smem[49152];   // 2 x 24KB gemm bufs
    const int bx = blockIdx.x, t = threadIdx.x;
    const int mt = bx & 127, ks = bx >> 7;
    const int r0 = mt * 64, kb = ks * 2048;

    // phase A1: convert own 64x2048 A-slice (linear, coalesced, 8KB runs)
#pragma unroll 4
    for (int it = 0; it < 32; ++it) {
        int id  = it * 512 + t;
        int row = id >> 8, c8 = id & 255;
        size_t off = (size_t)(r0 + row) * NN + kb + c8 * 8;
        f32x4 a = *(const f32x4*)(S + off);
        f32x4 b = *(const f32x4*)(S + off + 4);
        u16x8 p;
#pragma unroll
        for (int j = 0; j < 4; ++j) { p[j] = f2bf(a[j]); p[j + 4] = f2bf(b[j]); }
        *(u16x8*)(S16 + off) = p;
    }
    // phase A2: prep 16 rows (y = h0*X, ZT0 = X^T bf16)
    {
        float* tile = (float*)smem;
        const int rp = bx * 16;
        const float h0 = coeff[0];
        const int row = t >> 5, colc = t & 31;
        f32x4 v = *(const f32x4*)(X + (size_t)(rp + row) * NF + colc * 4);
        *(f32x4*)&tile[row * 132 + colc * 4] = v;
        *(f32x4*)(y + (size_t)(rp + row) * NF + colc * 4) = v * h0;
        __syncthreads();
        if (t < 256) {
            const int c = t >> 1, rh = t & 1;
            u16x8 pk;
#pragma unroll
            for (int e = 0; e < 8; ++e) pk[e] = f2bf(tile[(rh * 8 + e) * 132 + c]);
            *(u16x8*)(ZT0 + (size_t)c * ZSTRIDE + rp + rh * 8) = pk;
        }
    }
    gridbar(bar, 0);

    mega_gemm(S16, ZT0, P, smem, mt, ks, t);
    gridbar(bar, 1);
    mega_combine(P, y, ZT1, coeff[1], smem, bx, t);
    gridbar(bar, 2);

    mega_gemm(S16, ZT1, P, smem, mt, ks, t);
    gridbar(bar, 3);
    mega_combine(P, y, ZT0, coeff[2], smem, bx, t);
    gridbar(bar, 4);

    mega_gemm(S16, ZT0, P, smem, mt, ks, t);
    gridbar(bar, 5);
    mega_combine(P, y, nullptr, coeff[3], smem, bx, t);
}

// ---------------- fallback multi-kernel path (small ws) ---------------------

__global__ __launch_bounds__(256) void k_convert(const float* __restrict__ S,
                                                 uint16_t* __restrict__ S16) {
    const size_t n8 = (size_t)NN * NN / 8;
    const size_t stride = (size_t)gridDim.x * 256;
    for (size_t i = (size_t)blockIdx.x * 256 + threadIdx.x; i < n8; i += stride) {
        f32x4 a = *(const f32x4*)(S + i * 8);
        f32x4 b = *(const f32x4*)(S + i * 8 + 4);
        u16x8 p;
#pragma unroll
        for (int j = 0; j < 4; ++j) { p[j] = f2bf(a[j]); p[j + 4] = f2bf(b[j]); }
        *(u16x8*)(S16 + i * 8) = p;
    }
}

__global__ __launch_bounds__(256) void k_prep(const float* __restrict__ X,
                                              const float* __restrict__ coeff,
                                              float* __restrict__ y,
                                              uint16_t* __restrict__ ZT0) {
    __shared__ float tile[16][NF + 4];
    const int t  = threadIdx.x;
    const int r0 = blockIdx.x * 16;
    const float h0 = coeff[0];
#pragma unroll
    for (int i = 0; i < 2; ++i) {
        int o   = (i * 256 + t) * 4;
        int row = o >> 7, col = o & 127;
        f32x4 v = *(const f32x4*)(X + (size_t)(r0 + row) * NF + col);
        *(f32x4*)&tile[row][col] = v;
        *(f32x4*)(y + (size_t)(r0 + row) * NF + col) = v * h0;
    }
    __syncthreads();
    const int c = t >> 1, rh = t & 1;
    u16x8 pk;
#pragma unroll
    for (int e = 0; e < 8; ++e) pk[e] = f2bf(tile[rh * 8 + e][c]);
    *(u16x8*)(ZT0 + (size_t)c * ZSTRIDE + r0 + rh * 8) = pk;
}

template<int KS>
__global__ __launch_bounds__(512, 4) void k_gemm_bf(
    const uint16_t* __restrict__ S16, const uint16_t* __restrict__ ZTin,
    float* __restrict__ P)
{
    __shared__ __align__(16) uint8_t smem[2][24576];
    const int t = threadIdx.x, lane = t & 63;
    const int w = t >> 6, m = lane & 15, g = lane >> 4;
    const int rt = w & 3, ch = w >> 2;
    const int mt = blockIdx.x & 127, ks = blockIdx.x >> 7;
    const int r0 = mt * 64;
    const int kb = ks * (NN / KS);
    constexpr int NT = (NN / KS) / 64;

    const int srow = t >> 3, sc = t & 7;
    const int scs  = (sc ^ (srow & 7)) << 3;
    const uint16_t* asrc = S16  + (size_t)(r0 + srow) * NN + kb + scs;
    const uint16_t* bsrc = ZTin + (size_t)srow * ZSTRIDE   + kb + scs;

    const int sw   = m & 7;
    const int aoff = (rt * 16 + m) * 128 + ((g ^ sw) << 4);
    const int bof  = 8192 + (ch * 64 + m) * 128 + ((g ^ sw) << 4);

    f32x4 acc[4] = {};
    gemm_core<NT>(asrc, bsrc, &smem[0][0], t, acc, aoff, bof);

    float* pb = P + ((size_t)ks * NN + r0 + rt * 16 + 4 * g) * NF + ch * 64 + m;
#pragma unroll
    for (int ct = 0; ct < 4; ++ct)
#pragma unroll
        for (int i = 0; i < 4; ++i)
            pb[(size_t)i * NF + ct * 16] = acc[ct][i];
}

template<int KS, bool WRITE_ZT>
__global__ __launch_bounds__(256) void k_combine(const float* __restrict__ P,
                                                 float* __restrict__ y,
                                                 uint16_t* __restrict__ ZTout,
                                                 const float* __restrict__ coeff,
                                                 int pass) {
    __shared__ float tile[16][NF + 4];
    const int t = threadIdx.x, r0 = blockIdx.x * 16;
    const float hk = coeff[pass];
    const int row = t >> 4, col = (t & 15) * 8;
    const size_t off = (size_t)(r0 + row) * NF + col;
    f32x4 s0 = *(const f32x4*)(P + off);
    f32x4 s1 = *(const f32x4*)(P + off + 4);
#pragma unroll
    for (int k = 1; k < KS; ++k) {
        s0 += *(const f32x4*)(P + (size_t)k * NN * NF + off);
        s1 += *(const f32x4*)(P + (size_t)k * NN * NF + off + 4);
    }
    float* yp = y + off;
    f32x4 y0 = *(const f32x4*)yp, y1 = *(const f32x4*)(yp + 4);
    *(f32x4*)yp       = y0 + hk * s0;
    *(f32x4*)(yp + 4) = y1 + hk * s1;
    if (WRITE_ZT) {
        *(f32x4*)&tile[row][col]     = s0;
        *(f32x4*)&tile[row][col + 4] = s1;
        __syncthreads();
        const int c = t >> 1, rh = t & 1;
        u16x8 pk;
#pragma unroll
        for (int e = 0; e < 8; ++e) pk[e] = f2bf(tile[rh * 8 + e][c]);
        *(u16x8*)(ZTout + (size_t)c * ZSTRIDE + r0 + rh * 8) = pk;
    }
}

template<int KS>
static void run_fallback(const float* X, const float* S, const float* coeff,
                         float* y, uint16_t* ZT0, uint16_t* ZT1, uint16_t* S16,
                         float* P, hipStream_t stream) {
    k_prep<<<dim3(512), dim3(256), 0, stream>>>(X, coeff, y, ZT0);
    k_convert<<<dim3(2048), dim3(256), 0, stream>>>(S, S16);
    k_gemm_bf<KS><<<dim3(128 * KS), dim3(512), 0, stream>>>(S16, ZT0, P);
    k_combine<KS, true ><<<dim3(512), dim3(256), 0, stream>>>(P, y, ZT1, coeff, 1);
    k_gemm_bf<KS><<<dim3(128 * KS), dim3(512), 0, stream>>>(S16, ZT1, P);
    k_combine<KS, true ><<<dim3(512), dim3(256), 0, stream>>>(P, y, ZT0, coeff, 2);
    k_gemm_bf<KS><<<dim3(128 * KS), dim3(512), 0, stream>>>(S16, ZT0, P);
    k_combine<KS, false><<<dim3(512), dim3(256), 0, stream>>>(P, y, nullptr, coeff, 3);
}

extern "C" void kernel_launch(void* const* d_in, const int* in_sizes, int n_in,
                              void* d_out, int out_size, void* d_ws, size_t ws_size,
                              hipStream_t stream) {
    const float* X     = (const float*)d_in[0];
    const float* S     = (const float*)d_in[1];
    const float* coeff = (const float*)d_in[2];
    float* y = (float*)d_out;

    uint8_t* ws = (uint8_t*)d_ws;
    const size_t zb     = ((size_t)NF * ZSTRIDE * sizeof(uint16_t) + 255) & ~(size_t)255;
    const size_t s16b   = (size_t)NN * NN * sizeof(uint16_t);
    const size_t base   = 2 * zb + s16b;
    const size_t pslice = (size_t)NN * NF * sizeof(float);
    uint16_t* ZT0 = (uint16_t*)ws;
    uint16_t* ZT1 = (uint16_t*)(ws + zb);
    uint16_t* S16 = (uint16_t*)(ws + 2 * zb);
    float*    P   = (float*)(ws + base);
    const size_t bar_off = base + 4 * pslice;

    if (ws_size >= bar_off + 256) {
        uint32_t* bar = (uint32_t*)(ws + bar_off);
        hipMemsetAsync(bar, 0, 64, stream);
        k_mega<<<dim3(GRID), dim3(512), 0, stream>>>(S, X, coeff, y,
                                                     ZT0, ZT1, S16, P, bar);
    } else if (ws_size >= base + 2 * pslice) {
        run_fallback<2>(X, S, coeff, y, ZT0, ZT1, S16, P, stream);
    } else {
        run_fallback<1>(X, S, coeff, y, ZT0, ZT1, S16, P, stream);
    }
}

// Round 8
// 196.450 us; speedup vs baseline: 3.4301x; 3.4301x over previous
//
#include <hip/hip_runtime.h>
#include <hip/hip_bf16.h>
#include <stdint.h>

// y = sum_{k=0}^{3} h_k * S^k X,  X [8192,128] f32, S [8192,8192] f32.
//   k_cvprep:  S f32 -> S16 bf16 (grid-stride, nontemporal f32 reads);
//              blocks <512 also do prep (y = h0*X ; ZT0 = X^T bf16)
//   3x: k_gemm_bf<KS=8> (BM=64,BN=128,BK=64, global_load_lds 16B, XOR-swizzled
//       LDS, 2-buffer counted-vmcnt, 48KB LDS -> 3 blocks/CU, grid 1024) -> P
//       + k_combine<8> (sum partials, y += h_k Z, ZT' = bf16(Z^T))

typedef __attribute__((ext_vector_type(8))) short     bf16x8;
typedef __attribute__((ext_vector_type(8))) uint16_t  u16x8;
typedef __attribute__((ext_vector_type(4))) float     f32x4;

#define NN 8192
#define NF 128
#define ZSTRIDE (8192 + 64)

#define WAITV(n) asm volatile("s_waitcnt vmcnt(" #n ")" ::: "memory")
#define WAITL0   asm volatile("s_waitcnt lgkmcnt(0)" ::: "memory")

__device__ inline uint16_t f2bf(float f) {
    uint32_t u = __builtin_bit_cast(uint32_t, f);
    u += 0x7fffu + ((u >> 16) & 1u);     // round-to-nearest-even
    return (uint16_t)(u >> 16);
}

__device__ inline void gl2lds16(const void* g, uint8_t* l) {
    __builtin_amdgcn_global_load_lds(
        (const __attribute__((address_space(1))) uint32_t*)g,
        (__attribute__((address_space(3))) uint32_t*)l,
        16, 0, 0);
}

__device__ inline bf16x8 ld16(const uint8_t* p) {
    return __builtin_bit_cast(bf16x8, *(const u16x8*)p);
}

// ---- convert S -> bf16 (+ prep on blocks < 512) ----------------------------
__global__ __launch_bounds__(256) void k_cvprep(const float* __restrict__ S,
                                                uint16_t* __restrict__ S16,
                                                const float* __restrict__ X,
                                                const float* __restrict__ coeff,
                                                float* __restrict__ y,
                                                uint16_t* __restrict__ ZT0) {
    __shared__ float tile[16][NF + 4];
    const int t = threadIdx.x, bx = blockIdx.x;

    if (bx < 512) {                       // prep: 16 rows of X -> y, ZT0
        const int r0 = bx * 16;
        const float h0 = coeff[0];
#pragma unroll
        for (int i = 0; i < 2; ++i) {
            int o   = (i * 256 + t) * 4;
            int row = o >> 7, col = o & 127;
            f32x4 v = *(const f32x4*)(X + (size_t)(r0 + row) * NF + col);
            *(f32x4*)&tile[row][col] = v;
            *(f32x4*)(y + (size_t)(r0 + row) * NF + col) = v * h0;
        }
        __syncthreads();
        const int c = t >> 1, rh = t & 1;
        u16x8 pk;
#pragma unroll
        for (int e = 0; e < 8; ++e) pk[e] = f2bf(tile[rh * 8 + e][c]);
        *(u16x8*)(ZT0 + (size_t)c * ZSTRIDE + r0 + rh * 8) = pk;
    }

    // convert: grid-stride over 8M 8-elem chunks (2048 blocks -> 16 iters)
    const size_t base = (size_t)bx * 256 + t;
    const size_t stride = (size_t)gridDim.x * 256;
#pragma unroll 4
    for (int it = 0; it < 16; ++it) {
        size_t i = base + (size_t)it * stride;
        f32x4 a = __builtin_nontemporal_load((const f32x4*)(S + i * 8));
        f32x4 b = __builtin_nontemporal_load((const f32x4*)(S + i * 8 + 4));
        u16x8 p;
#pragma unroll
        for (int j = 0; j < 4; ++j) { p[j] = f2bf(a[j]); p[j + 4] = f2bf(b[j]); }
        *(u16x8*)(S16 + i * 8) = p;
    }
}

// ---- shared GEMM core: 2-buffer counted-vmcnt K-loop -----------------------
template<int NT>
__device__ inline void gemm_core(const uint16_t* asrc, const uint16_t* bsrc,
                                 uint8_t* smem, int t, f32x4 (&acc)[4],
                                 int aoff, int bof) {
    auto stage = [&](int buf, int kt) {
        const int ko = kt * 64;
        uint8_t* b = smem + buf * 24576;
        gl2lds16(asrc + ko, b + t * 16);
        gl2lds16(bsrc + ko, b + 8192 + t * 16);
        gl2lds16(bsrc + (size_t)64 * ZSTRIDE + ko, b + 16384 + t * 16);
    };
    stage(0, 0);
    int cur = 0;
#pragma unroll 1
    for (int kt = 0; kt < NT; ++kt) {
        if (kt + 1 < NT) {
            stage(cur ^ 1, kt + 1);
            WAITV(3);                 // stage(kt) done; stage(kt+1) in flight
        } else {
            WAITV(0);
        }
        __builtin_amdgcn_s_barrier();
        __builtin_amdgcn_sched_barrier(0);
        const uint8_t* bb = smem + cur * 24576;
        bf16x8 a0 = ld16(bb + aoff);
        bf16x8 a1 = ld16(bb + (aoff ^ 64));
#pragma unroll
        for (int ct = 0; ct < 4; ++ct) {
            acc[ct] = __builtin_amdgcn_mfma_f32_16x16x32_bf16(
                a0, ld16(bb + bof + ct * 16 * 128), acc[ct], 0, 0, 0);
            acc[ct] = __builtin_amdgcn_mfma_f32_16x16x32_bf16(
                a1, ld16(bb + ((bof + ct * 16 * 128) ^ 64)), acc[ct], 0, 0, 0);
        }
        WAITL0;                       // my reads of buf landed
        __builtin_amdgcn_sched_barrier(0);
        __builtin_amdgcn_s_barrier(); // everyone done reading buf
        cur ^= 1;
    }
}

// ---- GEMM pass: P[ks] = S16[64 rows, kslice] * Z[kslice, :] ----------------
template<int KS>
__global__ __launch_bounds__(512, 4) void k_gemm_bf(
    const uint16_t* __restrict__ S16, const uint16_t* __restrict__ ZTin,
    float* __restrict__ P)
{
    __shared__ __align__(16) uint8_t smem[2][24576];   // 48KB -> 3 blocks/CU
    const int t = threadIdx.x, lane = t & 63;
    const int w = t >> 6, m = lane & 15, g = lane >> 4;
    const int rt = w & 3, ch = w >> 2;
    const int mt = blockIdx.x & 127, ks = blockIdx.x >> 7;
    const int r0 = mt * 64;
    const int kb = ks * (NN / KS);
    constexpr int NT = (NN / KS) / 64;

    const int srow = t >> 3, sc = t & 7;
    const int scs  = (sc ^ (srow & 7)) << 3;
    const uint16_t* asrc = S16  + (size_t)(r0 + srow) * NN + kb + scs;
    const uint16_t* bsrc = ZTin + (size_t)srow * ZSTRIDE   + kb + scs;

    const int sw   = m & 7;
    const int aoff = (rt * 16 + m) * 128 + ((g ^ sw) << 4);
    const int bof  = 8192 + (ch * 64 + m) * 128 + ((g ^ sw) << 4);

    f32x4 acc[4] = {};
    gemm_core<NT>(asrc, bsrc, &smem[0][0], t, acc, aoff, bof);

    float* pb = P + ((size_t)ks * NN + r0 + rt * 16 + 4 * g) * NF + ch * 64 + m;
#pragma unroll
    for (int ct = 0; ct < 4; ++ct)
#pragma unroll
        for (int i = 0; i < 4; ++i)
            pb[(size_t)i * NF + ct * 16] = acc[ct][i];
}

// ---- combine: Z = sum_ks P ; y += h*Z ; ZT' = bf16(Z^T) --------------------
template<int KS, bool WRITE_ZT>
__global__ __launch_bounds__(256) void k_combine(const float* __restrict__ P,
                                                 float* __restrict__ y,
                                                 uint16_t* __restrict__ ZTout,
                                                 const float* __restrict__ coeff,
                                                 int pass) {
    __shared__ float tile[16][NF + 4];
    const int t = threadIdx.x, r0 = blockIdx.x * 16;
    const float hk = coeff[pass];
    const int row = t >> 4, col = (t & 15) * 8;
    const size_t off = (size_t)(r0 + row) * NF + col;
    f32x4 s0 = *(const f32x4*)(P + off);
    f32x4 s1 = *(const f32x4*)(P + off + 4);
#pragma unroll
    for (int k = 1; k < KS; ++k) {
        s0 += *(const f32x4*)(P + (size_t)k * NN * NF + off);
        s1 += *(const f32x4*)(P + (size_t)k * NN * NF + off + 4);
    }
    float* yp = y + off;
    f32x4 y0 = *(const f32x4*)yp, y1 = *(const f32x4*)(yp + 4);
    *(f32x4*)yp       = y0 + hk * s0;
    *(f32x4*)(yp + 4) = y1 + hk * s1;
    if (WRITE_ZT) {
        *(f32x4*)&tile[row][col]     = s0;
        *(f32x4*)&tile[row][col + 4] = s1;
        __syncthreads();
        const int c = t >> 1, rh = t & 1;
        u16x8 pk;
#pragma unroll
        for (int e = 0; e < 8; ++e) pk[e] = f2bf(tile[rh * 8 + e][c]);
        *(u16x8*)(ZTout + (size_t)c * ZSTRIDE + r0 + rh * 8) = pk;
    }
}

template<int KS>
static void run(const float* X, const float* S, const float* coeff, float* y,
                uint16_t* ZT0, uint16_t* ZT1, uint16_t* S16, float* P,
                hipStream_t stream) {
    k_cvprep<<<dim3(2048), dim3(256), 0, stream>>>(S, S16, X, coeff, y, ZT0);
    k_gemm_bf<KS><<<dim3(128 * KS), dim3(512), 0, stream>>>(S16, ZT0, P);
    k_combine<KS, true ><<<dim3(512), dim3(256), 0, stream>>>(P, y, ZT1, coeff, 1);
    k_gemm_bf<KS><<<dim3(128 * KS), dim3(512), 0, stream>>>(S16, ZT1, P);
    k_combine<KS, true ><<<dim3(512), dim3(256), 0, stream>>>(P, y, ZT0, coeff, 2);
    k_gemm_bf<KS><<<dim3(128 * KS), dim3(512), 0, stream>>>(S16, ZT0, P);
    k_combine<KS, false><<<dim3(512), dim3(256), 0, stream>>>(P, y, nullptr, coeff, 3);
}

extern "C" void kernel_launch(void* const* d_in, const int* in_sizes, int n_in,
                              void* d_out, int out_size, void* d_ws, size_t ws_size,
                              hipStream_t stream) {
    const float* X     = (const float*)d_in[0];
    const float* S     = (const float*)d_in[1];
    const float* coeff = (const float*)d_in[2];
    float* y = (float*)d_out;

    uint8_t* ws = (uint8_t*)d_ws;
    const size_t zb     = ((size_t)NF * ZSTRIDE * sizeof(uint16_t) + 255) & ~(size_t)255;
    const size_t s16b   = (size_t)NN * NN * sizeof(uint16_t);
    const size_t base   = 2 * zb + s16b;
    const size_t pslice = (size_t)NN * NF * sizeof(float);
    uint16_t* ZT0 = (uint16_t*)ws;
    uint16_t* ZT1 = (uint16_t*)(ws + zb);
    uint16_t* S16 = (uint16_t*)(ws + 2 * zb);
    float*    P   = (float*)(ws + base);

    if (ws_size >= base + 8 * pslice)
        run<8>(X, S, coeff, y, ZT0, ZT1, S16, P, stream);
    else if (ws_size >= base + 4 * pslice)
        run<4>(X, S, coeff, y, ZT0, ZT1, S16, P, stream);
    else if (ws_size >= base + 2 * pslice)
        run<2>(X, S, coeff, y, ZT0, ZT1, S16, P, stream);
    else
        run<1>(X, S, coeff, y, ZT0, ZT1, S16, P, stream);
}